// Round 1
// baseline (325.340 us; speedup 1.0000x reference)
//
#include <hip/hip_runtime.h>

// MSE-sum loss: out[0] = 0.5 * sum((a[i]-b[i])^2), n = 40e6 fp32 per input.
//
// R6 analysis: rocprof top-5 dispatches are ALL harness fill kernels (93 us,
// 640 MB poison writes @ 6.86 TB/s). mse_stage1 is < 93 us (> 3.4 TB/s
// effective) -- the 299 us total is mostly fixed harness work. Changes:
//   1. Revert nontemporal loads (296.7 -> 299.2 regression; the 640 MB poison
//      fill thrashes L3 every iteration anyway, nt gains nothing).
//   2. Deeper batching: 16 x global_load_dwordx4 in flight per thread
//      (64 KB per block vs 32 KB), guard-free main path via uniform branch,
//      half the blocks -> half the block-reduce tails and partials.
// Prediction: stage1 ~50-65 us @ ~5-6.5 TB/s; total 299 -> ~285 if kernel
// portion mattered; total unchanged (+-3) => harness-fill-bound (roofline).

typedef float fvec4 __attribute__((ext_vector_type(4)));

#define V4_PER_BLOCK 2048L   // 256 threads * 8 float4 each, per input array

__global__ __launch_bounds__(256) void mse_stage1(const fvec4* __restrict__ a4,
                                                  const fvec4* __restrict__ b4,
                                                  float* __restrict__ partial,
                                                  long n4) {
    const int t = threadIdx.x;
    const long base = (long)blockIdx.x * V4_PER_BLOCK;

    float acc0 = 0.0f, acc1 = 0.0f, acc2 = 0.0f, acc3 = 0.0f;

    if (base + V4_PER_BLOCK <= n4) {
        // Guard-free main path: 16 independent global_load_dwordx4.
        // Each load instruction covers 1 KB contiguous per quarter-wave group
        // (lane i reads base + u*256 + i -> perfectly coalesced).
        fvec4 x0 = a4[base + 0*256 + t];
        fvec4 x1 = a4[base + 1*256 + t];
        fvec4 x2 = a4[base + 2*256 + t];
        fvec4 x3 = a4[base + 3*256 + t];
        fvec4 x4 = a4[base + 4*256 + t];
        fvec4 x5 = a4[base + 5*256 + t];
        fvec4 x6 = a4[base + 6*256 + t];
        fvec4 x7 = a4[base + 7*256 + t];
        fvec4 y0 = b4[base + 0*256 + t];
        fvec4 y1 = b4[base + 1*256 + t];
        fvec4 y2 = b4[base + 2*256 + t];
        fvec4 y3 = b4[base + 3*256 + t];
        fvec4 y4 = b4[base + 4*256 + t];
        fvec4 y5 = b4[base + 5*256 + t];
        fvec4 y6 = b4[base + 6*256 + t];
        fvec4 y7 = b4[base + 7*256 + t];

        fvec4 d;
        d = x0 - y0; acc0 = fmaf(d.x, d.x, acc0); acc1 = fmaf(d.y, d.y, acc1);
                     acc2 = fmaf(d.z, d.z, acc2); acc3 = fmaf(d.w, d.w, acc3);
        d = x1 - y1; acc0 = fmaf(d.x, d.x, acc0); acc1 = fmaf(d.y, d.y, acc1);
                     acc2 = fmaf(d.z, d.z, acc2); acc3 = fmaf(d.w, d.w, acc3);
        d = x2 - y2; acc0 = fmaf(d.x, d.x, acc0); acc1 = fmaf(d.y, d.y, acc1);
                     acc2 = fmaf(d.z, d.z, acc2); acc3 = fmaf(d.w, d.w, acc3);
        d = x3 - y3; acc0 = fmaf(d.x, d.x, acc0); acc1 = fmaf(d.y, d.y, acc1);
                     acc2 = fmaf(d.z, d.z, acc2); acc3 = fmaf(d.w, d.w, acc3);
        d = x4 - y4; acc0 = fmaf(d.x, d.x, acc0); acc1 = fmaf(d.y, d.y, acc1);
                     acc2 = fmaf(d.z, d.z, acc2); acc3 = fmaf(d.w, d.w, acc3);
        d = x5 - y5; acc0 = fmaf(d.x, d.x, acc0); acc1 = fmaf(d.y, d.y, acc1);
                     acc2 = fmaf(d.z, d.z, acc2); acc3 = fmaf(d.w, d.w, acc3);
        d = x6 - y6; acc0 = fmaf(d.x, d.x, acc0); acc1 = fmaf(d.y, d.y, acc1);
                     acc2 = fmaf(d.z, d.z, acc2); acc3 = fmaf(d.w, d.w, acc3);
        d = x7 - y7; acc0 = fmaf(d.x, d.x, acc0); acc1 = fmaf(d.y, d.y, acc1);
                     acc2 = fmaf(d.z, d.z, acc2); acc3 = fmaf(d.w, d.w, acc3);
    } else {
        // Tail block only (uniform branch): guarded loads.
        #pragma unroll
        for (int u = 0; u < 8; ++u) {
            const long i = base + (long)u * 256 + t;
            if (i < n4) {
                fvec4 xv = a4[i];
                fvec4 yv = b4[i];
                fvec4 d = xv - yv;
                acc0 = fmaf(d.x, d.x, acc0);
                acc1 = fmaf(d.y, d.y, acc1);
                acc2 = fmaf(d.z, d.z, acc2);
                acc3 = fmaf(d.w, d.w, acc3);
            }
        }
    }

    float acc = (acc0 + acc1) + (acc2 + acc3);

    // wave-64 shuffle reduction
    #pragma unroll
    for (int off = 32; off > 0; off >>= 1)
        acc += __shfl_down(acc, off, 64);

    __shared__ float wave_sums[4];
    const int lane = t & 63;
    const int wid  = t >> 6;
    if (lane == 0) wave_sums[wid] = acc;
    __syncthreads();

    if (t == 0)
        partial[blockIdx.x] = (wave_sums[0] + wave_sums[1]) + (wave_sums[2] + wave_sums[3]);
}

__global__ __launch_bounds__(256) void mse_stage2(const float* __restrict__ partial,
                                                  float* __restrict__ out,
                                                  int m) {
    float acc = 0.0f;
    for (int i = threadIdx.x; i < m; i += 256)
        acc += partial[i];

    #pragma unroll
    for (int off = 32; off > 0; off >>= 1)
        acc += __shfl_down(acc, off, 64);

    __shared__ float wave_sums[4];
    const int lane = threadIdx.x & 63;
    const int wid  = threadIdx.x >> 6;
    if (lane == 0) wave_sums[wid] = acc;
    __syncthreads();

    if (threadIdx.x == 0)
        out[0] = 0.5f * ((wave_sums[0] + wave_sums[1]) + (wave_sums[2] + wave_sums[3]));
}

extern "C" void kernel_launch(void* const* d_in, const int* in_sizes, int n_in,
                              void* d_out, int out_size, void* d_ws, size_t ws_size,
                              hipStream_t stream) {
    const fvec4* a4 = (const fvec4*)d_in[0];
    const fvec4* b4 = (const fvec4*)d_in[1];
    float* out = (float*)d_out;
    float* partial = (float*)d_ws;

    const long n = (long)in_sizes[0];        // 40,000,000 floats per input
    const long n4 = n >> 2;                  // 10,000,000 float4 groups (n % 4 == 0)
    const int blocks = (int)((n4 + V4_PER_BLOCK - 1) / V4_PER_BLOCK);   // 4883

    mse_stage1<<<blocks, 256, 0, stream>>>(a4, b4, partial, n4);
    mse_stage2<<<1, 256, 0, stream>>>(partial, out, blocks);
}

// Round 2
// 294.518 us; speedup vs baseline: 1.1047x; 1.1047x over previous
//
#include <hip/hip_runtime.h>

// MSE-sum loss: out[0] = 0.5 * sum((a[i]-b[i])^2), n = 40e6 fp32 per input.
//
// R7 analysis: R6 (nt removed, deeper batching) regressed stage1 to 112 us =
// 2.86 TB/s -- EXACTLY the R1-R3 non-nt plateau. Batching didn't move it;
// the nontemporal bit was the prior session's real win (stage1 <93 us with nt).
// Mechanism: without nt both 160 MB streams allocate into the 256 MB L3 and
// miss/evict arbitration caps reads at ~2.9 TB/s; nt streams past L3.
// Change: restore nt loads on all global reads, keep R6's guard-free 16-load
// main path and halved block count.
// Prediction: stage1 ~80-90 us (>=3.5 TB/s), total ~290-297.

typedef float fvec4 __attribute__((ext_vector_type(4)));

#define V4_PER_BLOCK 2048L   // 256 threads * 8 float4 each, per input array

__global__ __launch_bounds__(256) void mse_stage1(const fvec4* __restrict__ a4,
                                                  const fvec4* __restrict__ b4,
                                                  float* __restrict__ partial,
                                                  long n4) {
    const int t = threadIdx.x;
    const long base = (long)blockIdx.x * V4_PER_BLOCK;

    float acc0 = 0.0f, acc1 = 0.0f, acc2 = 0.0f, acc3 = 0.0f;

    if (base + V4_PER_BLOCK <= n4) {
        // Guard-free main path: 16 independent nontemporal global_load_dwordx4,
        // a/b interleaved pairwise (proven R0 pattern). Lane i reads
        // base + u*256 + i -> perfectly coalesced 1 KB per quarter-wave.
        fvec4 x0 = __builtin_nontemporal_load(&a4[base + 0*256 + t]);
        fvec4 y0 = __builtin_nontemporal_load(&b4[base + 0*256 + t]);
        fvec4 x1 = __builtin_nontemporal_load(&a4[base + 1*256 + t]);
        fvec4 y1 = __builtin_nontemporal_load(&b4[base + 1*256 + t]);
        fvec4 x2 = __builtin_nontemporal_load(&a4[base + 2*256 + t]);
        fvec4 y2 = __builtin_nontemporal_load(&b4[base + 2*256 + t]);
        fvec4 x3 = __builtin_nontemporal_load(&a4[base + 3*256 + t]);
        fvec4 y3 = __builtin_nontemporal_load(&b4[base + 3*256 + t]);
        fvec4 x4 = __builtin_nontemporal_load(&a4[base + 4*256 + t]);
        fvec4 y4 = __builtin_nontemporal_load(&b4[base + 4*256 + t]);
        fvec4 x5 = __builtin_nontemporal_load(&a4[base + 5*256 + t]);
        fvec4 y5 = __builtin_nontemporal_load(&b4[base + 5*256 + t]);
        fvec4 x6 = __builtin_nontemporal_load(&a4[base + 6*256 + t]);
        fvec4 y6 = __builtin_nontemporal_load(&b4[base + 6*256 + t]);
        fvec4 x7 = __builtin_nontemporal_load(&a4[base + 7*256 + t]);
        fvec4 y7 = __builtin_nontemporal_load(&b4[base + 7*256 + t]);

        fvec4 d;
        d = x0 - y0; acc0 = fmaf(d.x, d.x, acc0); acc1 = fmaf(d.y, d.y, acc1);
                     acc2 = fmaf(d.z, d.z, acc2); acc3 = fmaf(d.w, d.w, acc3);
        d = x1 - y1; acc0 = fmaf(d.x, d.x, acc0); acc1 = fmaf(d.y, d.y, acc1);
                     acc2 = fmaf(d.z, d.z, acc2); acc3 = fmaf(d.w, d.w, acc3);
        d = x2 - y2; acc0 = fmaf(d.x, d.x, acc0); acc1 = fmaf(d.y, d.y, acc1);
                     acc2 = fmaf(d.z, d.z, acc2); acc3 = fmaf(d.w, d.w, acc3);
        d = x3 - y3; acc0 = fmaf(d.x, d.x, acc0); acc1 = fmaf(d.y, d.y, acc1);
                     acc2 = fmaf(d.z, d.z, acc2); acc3 = fmaf(d.w, d.w, acc3);
        d = x4 - y4; acc0 = fmaf(d.x, d.x, acc0); acc1 = fmaf(d.y, d.y, acc1);
                     acc2 = fmaf(d.z, d.z, acc2); acc3 = fmaf(d.w, d.w, acc3);
        d = x5 - y5; acc0 = fmaf(d.x, d.x, acc0); acc1 = fmaf(d.y, d.y, acc1);
                     acc2 = fmaf(d.z, d.z, acc2); acc3 = fmaf(d.w, d.w, acc3);
        d = x6 - y6; acc0 = fmaf(d.x, d.x, acc0); acc1 = fmaf(d.y, d.y, acc1);
                     acc2 = fmaf(d.z, d.z, acc2); acc3 = fmaf(d.w, d.w, acc3);
        d = x7 - y7; acc0 = fmaf(d.x, d.x, acc0); acc1 = fmaf(d.y, d.y, acc1);
                     acc2 = fmaf(d.z, d.z, acc2); acc3 = fmaf(d.w, d.w, acc3);
    } else {
        // Tail block only (uniform branch): guarded nt loads.
        #pragma unroll
        for (int u = 0; u < 8; ++u) {
            const long i = base + (long)u * 256 + t;
            if (i < n4) {
                fvec4 xv = __builtin_nontemporal_load(&a4[i]);
                fvec4 yv = __builtin_nontemporal_load(&b4[i]);
                fvec4 d = xv - yv;
                acc0 = fmaf(d.x, d.x, acc0);
                acc1 = fmaf(d.y, d.y, acc1);
                acc2 = fmaf(d.z, d.z, acc2);
                acc3 = fmaf(d.w, d.w, acc3);
            }
        }
    }

    float acc = (acc0 + acc1) + (acc2 + acc3);

    // wave-64 shuffle reduction
    #pragma unroll
    for (int off = 32; off > 0; off >>= 1)
        acc += __shfl_down(acc, off, 64);

    __shared__ float wave_sums[4];
    const int lane = t & 63;
    const int wid  = t >> 6;
    if (lane == 0) wave_sums[wid] = acc;
    __syncthreads();

    if (t == 0)
        partial[blockIdx.x] = (wave_sums[0] + wave_sums[1]) + (wave_sums[2] + wave_sums[3]);
}

__global__ __launch_bounds__(256) void mse_stage2(const float* __restrict__ partial,
                                                  float* __restrict__ out,
                                                  int m) {
    float acc = 0.0f;
    for (int i = threadIdx.x; i < m; i += 256)
        acc += partial[i];

    #pragma unroll
    for (int off = 32; off > 0; off >>= 1)
        acc += __shfl_down(acc, off, 64);

    __shared__ float wave_sums[4];
    const int lane = threadIdx.x & 63;
    const int wid  = threadIdx.x >> 6;
    if (lane == 0) wave_sums[wid] = acc;
    __syncthreads();

    if (threadIdx.x == 0)
        out[0] = 0.5f * ((wave_sums[0] + wave_sums[1]) + (wave_sums[2] + wave_sums[3]));
}

extern "C" void kernel_launch(void* const* d_in, const int* in_sizes, int n_in,
                              void* d_out, int out_size, void* d_ws, size_t ws_size,
                              hipStream_t stream) {
    const fvec4* a4 = (const fvec4*)d_in[0];
    const fvec4* b4 = (const fvec4*)d_in[1];
    float* out = (float*)d_out;
    float* partial = (float*)d_ws;

    const long n = (long)in_sizes[0];        // 40,000,000 floats per input
    const long n4 = n >> 2;                  // 10,000,000 float4 groups (n % 4 == 0)
    const int blocks = (int)((n4 + V4_PER_BLOCK - 1) / V4_PER_BLOCK);   // 4883

    mse_stage1<<<blocks, 256, 0, stream>>>(a4, b4, partial, n4);
    mse_stage2<<<1, 256, 0, stream>>>(partial, out, blocks);
}

// Round 3
// 293.822 us; speedup vs baseline: 1.1073x; 1.0024x over previous
//
#include <hip/hip_runtime.h>

// MSE-sum loss: out[0] = 0.5 * sum((a[i]-b[i])^2), n = 40e6 fp32 per input.
//
// R8 analysis: R7 confirmed nt is worth +30 us (stage1 113 -> ~82 us, 3.9 TB/s).
// Gap to read floor (~49 us @ 6.5 TB/s) remains. Machine sustains 6.86 TB/s
// write-only (fill) and 6.29 TB/s copy, so 3.9 TB/s read is a pattern problem,
// not a HW ceiling. Suspect: chip-wide pairwise a/b interleave at 1 KB grain
// fragments HBM channel/row bursts across two streams 160 MB apart.
// Changes (one pattern variable):
//   1. Burst-group: 8 consecutive a-loads then 8 b-loads per round.
//   2. Odd blocks swap pointer order ((a-b)^2 == (b-a)^2) to decorrelate the
//      two streams' instantaneous channel demand.
//   3. 128 KB per block (2442 blocks, 32 loads/thread, 2 rounds) -> longer
//      bursts, half the reduce tails.
// Prediction: stage1 ~60-70 us, total ~275-285 if pattern is the lever;
// total ~294 unchanged => nt-read-path plateau, not pattern.

typedef float fvec4 __attribute__((ext_vector_type(4)));

#define V4_PER_BLOCK 4096L   // 256 threads * 16 float4 each, per input array

__global__ __launch_bounds__(256) void mse_stage1(const fvec4* __restrict__ a4,
                                                  const fvec4* __restrict__ b4,
                                                  float* __restrict__ partial,
                                                  long n4) {
    const int t = threadIdx.x;
    const long base = (long)blockIdx.x * V4_PER_BLOCK;

    // (a-b)^2 == (b-a)^2: odd blocks read b-stream first to decorrelate
    // the two streams' instantaneous channel pressure.
    const fvec4* __restrict__ p = (blockIdx.x & 1) ? b4 : a4;
    const fvec4* __restrict__ q = (blockIdx.x & 1) ? a4 : b4;

    float acc0 = 0.0f, acc1 = 0.0f, acc2 = 0.0f, acc3 = 0.0f;

    if (base + V4_PER_BLOCK <= n4) {
        #pragma unroll
        for (int r = 0; r < 2; ++r) {
            fvec4 x[8], y[8];
            // 8-load burst from stream p (8 KB contiguous per quarter-wave grp)
            #pragma unroll
            for (int u = 0; u < 8; ++u)
                x[u] = __builtin_nontemporal_load(&p[base + (r * 8 + u) * 256 + t]);
            // 8-load burst from stream q
            #pragma unroll
            for (int u = 0; u < 8; ++u)
                y[u] = __builtin_nontemporal_load(&q[base + (r * 8 + u) * 256 + t]);
            #pragma unroll
            for (int u = 0; u < 8; ++u) {
                fvec4 d = x[u] - y[u];
                acc0 = fmaf(d.x, d.x, acc0);
                acc1 = fmaf(d.y, d.y, acc1);
                acc2 = fmaf(d.z, d.z, acc2);
                acc3 = fmaf(d.w, d.w, acc3);
            }
        }
    } else {
        // Tail block only (uniform branch): guarded nt loads.
        #pragma unroll 4
        for (int u = 0; u < 16; ++u) {
            const long i = base + (long)u * 256 + t;
            if (i < n4) {
                fvec4 xv = __builtin_nontemporal_load(&p[i]);
                fvec4 yv = __builtin_nontemporal_load(&q[i]);
                fvec4 d = xv - yv;
                acc0 = fmaf(d.x, d.x, acc0);
                acc1 = fmaf(d.y, d.y, acc1);
                acc2 = fmaf(d.z, d.z, acc2);
                acc3 = fmaf(d.w, d.w, acc3);
            }
        }
    }

    float acc = (acc0 + acc1) + (acc2 + acc3);

    // wave-64 shuffle reduction
    #pragma unroll
    for (int off = 32; off > 0; off >>= 1)
        acc += __shfl_down(acc, off, 64);

    __shared__ float wave_sums[4];
    const int lane = t & 63;
    const int wid  = t >> 6;
    if (lane == 0) wave_sums[wid] = acc;
    __syncthreads();

    if (t == 0)
        partial[blockIdx.x] = (wave_sums[0] + wave_sums[1]) + (wave_sums[2] + wave_sums[3]);
}

__global__ __launch_bounds__(256) void mse_stage2(const float* __restrict__ partial,
                                                  float* __restrict__ out,
                                                  int m) {
    float acc = 0.0f;
    for (int i = threadIdx.x; i < m; i += 256)
        acc += partial[i];

    #pragma unroll
    for (int off = 32; off > 0; off >>= 1)
        acc += __shfl_down(acc, off, 64);

    __shared__ float wave_sums[4];
    const int lane = threadIdx.x & 63;
    const int wid  = threadIdx.x >> 6;
    if (lane == 0) wave_sums[wid] = acc;
    __syncthreads();

    if (threadIdx.x == 0)
        out[0] = 0.5f * ((wave_sums[0] + wave_sums[1]) + (wave_sums[2] + wave_sums[3]));
}

extern "C" void kernel_launch(void* const* d_in, const int* in_sizes, int n_in,
                              void* d_out, int out_size, void* d_ws, size_t ws_size,
                              hipStream_t stream) {
    const fvec4* a4 = (const fvec4*)d_in[0];
    const fvec4* b4 = (const fvec4*)d_in[1];
    float* out = (float*)d_out;
    float* partial = (float*)d_ws;

    const long n = (long)in_sizes[0];        // 40,000,000 floats per input
    const long n4 = n >> 2;                  // 10,000,000 float4 groups (n % 4 == 0)
    const int blocks = (int)((n4 + V4_PER_BLOCK - 1) / V4_PER_BLOCK);   // 2442

    mse_stage1<<<blocks, 256, 0, stream>>>(a4, b4, partial, n4);
    mse_stage2<<<1, 256, 0, stream>>>(partial, out, blocks);
}